// Round 3
// baseline (123.645 us; speedup 1.0000x reference)
//
#include <hip/hip_runtime.h>
#include <hip/hip_bf16.h>
#include <cstdint>
#include <cstddef>

#define DPc 0.05f

typedef __attribute__((ext_vector_type(8))) short bf8_t;   // 8 bf16
typedef __attribute__((ext_vector_type(4))) float f4_t;    // 4 fp32 acc
typedef long i64;
typedef __attribute__((ext_vector_type(2))) long i64x2;
typedef __attribute__((ext_vector_type(4))) int i32x4;
typedef __attribute__((ext_vector_type(8))) int i32x8;
typedef __attribute__((ext_vector_type(16))) float f32x16;

__device__ __forceinline__ short f2bf(float x) {
  __hip_bfloat16 h = __float2bfloat16(x);
  return *reinterpret_cast<short*>(&h);
}
__device__ __forceinline__ float bf2f(short x) {
  __hip_bfloat16 h;
  *reinterpret_cast<short*>(&h) = x;
  return __bfloat162float(h);
}

__device__ __forceinline__ void gload_lds16(const void* g, void* l) {
  __builtin_amdgcn_global_load_lds(
      (const __attribute__((address_space(1))) unsigned int*)g,
      (__attribute__((address_space(3))) unsigned int*)l,
      16, 0, 0);
}

// Per-row: f32 sum of squares + bf16 cast; x rows also emit a PLAIN row-major
// fp8-e4m3 copy (the MX-scaled 32x32x64 MFMA consumes per-lane-contiguous
// 32-byte K blocks).
__global__ void prep_rows_all(const float* __restrict__ X,
                              const float* __restrict__ Kn, int D, int N,
                              short* __restrict__ Xb, short* __restrict__ Kb,
                              char* __restrict__ Xq,
                              float* __restrict__ nb, float* __restrict__ na) {
  const int row = blockIdx.x;
  const int tid = threadIdx.x;
  const float* xr;
  short* br;
  char* qr = nullptr;
  float* nrm;
  if (row < N) {
    xr = X + (size_t)row * D;
    br = Xb + (size_t)row * D;
    qr = Xq + (size_t)row * D;
    nrm = nb + row;
  } else {
    const int r2 = row - N;
    xr = Kn + (size_t)r2 * D;
    br = Kb + (size_t)r2 * D;
    nrm = na + r2;
  }
  float s = 0.f;
  for (int c = tid * 4; c < D; c += 256 * 4) {
    const float4 v = *reinterpret_cast<const float4*>(xr + c);
    s += v.x * v.x + v.y * v.y + v.z * v.z + v.w * v.w;
    short4 b;
    b.x = f2bf(v.x); b.y = f2bf(v.y); b.z = f2bf(v.z); b.w = f2bf(v.w);
    *reinterpret_cast<short4*>(br + c) = b;
    if (qr) {
      int p = __builtin_amdgcn_cvt_pk_fp8_f32(v.x, v.y, 0, false);
      p = __builtin_amdgcn_cvt_pk_fp8_f32(v.z, v.w, p, true);
      *reinterpret_cast<int*>(qr + c) = p;
    }
  }
#pragma unroll
  for (int off = 32; off > 0; off >>= 1) s += __shfl_down(s, off);
  __shared__ float wsum[4];
  if ((tid & 63) == 0) wsum[tid >> 6] = s;
  __syncthreads();
  if (tid == 0) *nrm = wsum[0] + wsum[1] + wsum[2] + wsum[3];
}

// ------------- 128x128-tile 2-phase NT GEMM (Tuu, MX-fp8) -------------------
// Clean T3 "minimum 2-phase" schedule replacing the 4-phase grp-overwrite
// lockstep (which profiling showed to be pure stall: ~1800 cyc/phase for
// 8 ds_reads + 2 MFMAs, duration invariant to MFMA rate AND occupancy).
// True double-buffer, 1-tile lead: stage tile t+1 into buf^1 at the TOP of
// tile t (pinned by sched_barrier so the ~200cyc L2 latency hides under this
// tile's ~1100cyc of MFMA issue), read all 16 b128 fragments + 8 MFMAs in ONE
// unfenced region (compiler emits fine-grained lgkmcnt), single vmcnt(0) +
// barrier pair per K-tile.  256 threads / 64 KiB LDS -> 2 blocks/CU.
// Same MX 32x32x64 MFMA (unit scales), same XOR-16B-chunk swizzle
// (pre-swizzled global source + linear global_load_lds dest, read applies
// chunk ^ (row&7)).
__global__ __launch_bounds__(256, 2) void gemm_nt8_tuu(
    const char* __restrict__ Aq, int Ndim, int KB,
    const float* __restrict__ nb, short* __restrict__ obf,
    float* __restrict__ prow) {
  __shared__ char tA[2][128 * 128];
  __shared__ char tB[2][128 * 128];
  const int ntn = Ndim / 128;
  const int tm = blockIdx.x / ntn;
  const int tn = blockIdx.x % ntn;
  const int tid = threadIdx.x;
  const int wave = tid >> 6;   // 0..3
  const int lane = tid & 63;
  const int wm = wave >> 1;    // 0..1  (64-row block)
  const int wn = wave & 1;     // 0..1  (64-col block)
  const int l31 = lane & 31;
  const int lh = lane >> 5;    // 0..1  (K-half within a 64-elem block)

  f32x16 acc[2][2];
#pragma unroll
  for (int m = 0; m < 2; ++m)
#pragma unroll
    for (int n = 0; n < 2; ++n) acc[m][n] = (f32x16)(0.f);

  const int srow = lane >> 3;          // 0..7
  const int sch = (lane & 7) ^ srow;   // pre-swizzled source 16B chunk
  const size_t arow0 = (size_t)tm * 128;
  const size_t brow0 = (size_t)tn * 128;

  // grp: 0 = A/mf0 rows, 1 = A/mf1 rows, 2 = B/nf0 rows, 3 = B/nf1 rows.
  // Each grp = 64 rows (two 32-row segments), 2 gloads/wave (8 rows each).
  auto stage = [&](int buf, int k0B, int grp) {
#pragma unroll
    for (int i = 0; i < 2; ++i) {
      const int lin = i * 32 + wave * 8;                     // 0..63
      const int row0 = ((lin >> 5) * 64) + (lin & 31) + ((grp & 1) * 32);
      const size_t base = (grp < 2) ? arow0 : brow0;
      char* dst = (grp < 2) ? &tA[buf][row0 * 128] : &tB[buf][row0 * 128];
      gload_lds16(Aq + (base + row0 + srow) * KB + k0B + sch * 16, dst);
    }
  };

  // Read-side swizzled chunk byte-offsets: chunk (q*4 + lh*2 + h) ^ (row&7).
  // row = 32*frag + l31 with 32|base => row&7 == l31&7 (lane-constant).
  int coff[2][2];
#pragma unroll
  for (int q = 0; q < 2; ++q)
#pragma unroll
    for (int h = 0; h < 2; ++h)
      coff[q][h] = (((q * 4 + lh * 2 + h) ^ (l31 & 7)) << 4);
  const int aoff = (wm * 64 + l31) * 128;
  const int boff = (wn * 64 + l31) * 128;

  auto rdA = [&](int buf, int mf, int q) -> i32x8 {
    const char* p = &tA[buf][aoff + mf * 32 * 128];
    const i32x4 lo = *reinterpret_cast<const i32x4*>(p + coff[q][0]);
    const i32x4 hi = *reinterpret_cast<const i32x4*>(p + coff[q][1]);
    i32x8 r;
    r[0] = lo[0]; r[1] = lo[1]; r[2] = lo[2]; r[3] = lo[3];
    r[4] = hi[0]; r[5] = hi[1]; r[6] = hi[2]; r[7] = hi[3];
    return r;
  };
  auto rdB = [&](int buf, int nf, int q) -> i32x8 {
    const char* p = &tB[buf][boff + nf * 32 * 128];
    const i32x4 lo = *reinterpret_cast<const i32x4*>(p + coff[q][0]);
    const i32x4 hi = *reinterpret_cast<const i32x4*>(p + coff[q][1]);
    i32x8 r;
    r[0] = lo[0]; r[1] = lo[1]; r[2] = lo[2]; r[3] = lo[3];
    r[4] = hi[0]; r[5] = hi[1]; r[6] = hi[2]; r[7] = hi[3];
    return r;
  };

#define MFMA_SC(A_, B_, C_)                                        \
  __builtin_amdgcn_mfma_scale_f32_32x32x64_f8f6f4(                 \
      (A_), (B_), (C_), 0, 0, 0, 0x7F7F7F7F, 0, 0x7F7F7F7F)

  const int NK = KB / 128;  // 8
#pragma unroll
  for (int g = 0; g < 4; ++g) stage(0, 0, g);
  asm volatile("s_waitcnt vmcnt(0)" ::: "memory");
  __builtin_amdgcn_s_barrier();
  __builtin_amdgcn_sched_barrier(0);

  for (int t = 0; t < NK; ++t) {
    const int cur = t & 1;
    // Prefetch tile t+1 into the NON-read buffer; pin the issue to the top
    // of the tile so its latency hides under this tile's MFMAs.
    if (t + 1 < NK) {
#pragma unroll
      for (int g = 0; g < 4; ++g) stage(cur ^ 1, (t + 1) * 128, g);
    }
    __builtin_amdgcn_sched_barrier(0);
    // One unfenced region: 16 ds_read_b128 + 8 MFMAs (distance-4 acc chains).
    i32x8 a00 = rdA(cur, 0, 0), a01 = rdA(cur, 0, 1);
    i32x8 a10 = rdA(cur, 1, 0), a11 = rdA(cur, 1, 1);
    i32x8 b00 = rdB(cur, 0, 0), b01 = rdB(cur, 0, 1);
    i32x8 b10 = rdB(cur, 1, 0), b11 = rdB(cur, 1, 1);
    __builtin_amdgcn_s_setprio(1);
    acc[0][0] = MFMA_SC(a00, b00, acc[0][0]);
    acc[0][1] = MFMA_SC(a00, b10, acc[0][1]);
    acc[1][0] = MFMA_SC(a10, b00, acc[1][0]);
    acc[1][1] = MFMA_SC(a10, b10, acc[1][1]);
    acc[0][0] = MFMA_SC(a01, b01, acc[0][0]);
    acc[0][1] = MFMA_SC(a01, b11, acc[0][1]);
    acc[1][0] = MFMA_SC(a11, b01, acc[1][0]);
    acc[1][1] = MFMA_SC(a11, b11, acc[1][1]);
    __builtin_amdgcn_s_setprio(0);
    // Next iteration reads buf^1: its loads must have landed.
    asm volatile("s_waitcnt vmcnt(0)" ::: "memory");
    __builtin_amdgcn_s_barrier();
    __builtin_amdgcn_sched_barrier(0);
  }
#undef MFMA_SC

  // Epilogue: 32x32 C layout: col = l31, row = (r&3) + 8*(r>>2) + 4*lh.
  float* lrs = reinterpret_cast<float*>(tA);  // dead LDS: [128 rows][2 wn]
#pragma unroll
  for (int mf = 0; mf < 2; ++mf) {
    float rsum[16];
#pragma unroll
    for (int r = 0; r < 16; ++r) rsum[r] = 0.f;
#pragma unroll
    for (int nf = 0; nf < 2; ++nf) {
      const int gcol = tn * 128 + wn * 64 + nf * 32 + l31;
#pragma unroll
      for (int r = 0; r < 16; ++r) {
        const int lr = (r & 3) + 8 * (r >> 2) + 4 * lh;
        const int gr = tm * 128 + wm * 64 + mf * 32 + lr;
        const float v = acc[mf][nf][r];
        const float tt = fmaxf(2.f * nb[gr] - 2.f * v, 0.f);
        float e = __expf(-DPc * sqrtf(tt));
        if (gr == gcol) e = 0.f;
        rsum[r] += e;
        obf[(size_t)gr * Ndim + gcol] = f2bf(e);
      }
    }
#pragma unroll
    for (int r = 0; r < 16; ++r) {
      float v = rsum[r];
      v += __shfl_xor(v, 1);
      v += __shfl_xor(v, 2);
      v += __shfl_xor(v, 4);
      v += __shfl_xor(v, 8);
      v += __shfl_xor(v, 16);
      if (l31 == 0) {
        const int lr = (r & 3) + 8 * (r >> 2) + 4 * lh;
        lrs[(wm * 64 + mf * 32 + lr) * 2 + wn] = v;
      }
    }
  }
  __syncthreads();
  if (tid < 128) {
    const float s = lrs[tid * 2 + 0] + lrs[tid * 2 + 1];
    prow[(size_t)tn * Ndim + tm * 128 + tid] = s;
  }
}

// ---------------- BMxBN-tile NT GEMM (Tul + P-application) ------------------
// EPI 1: Tul f32 = __expf(-dp*sqrt(max(nb_i-2v+na_j,0))).
// EPI 2: y = v*invS[gcol]+PulT (fallback); FINAL ? out^T f32 : Z bf16.
// EPI 8: of32[split-partial] = v.
template <int WAVES, int EPI, bool FINAL, int SPLITK, int BM, int BN, int BK>
__global__ __launch_bounds__(WAVES * 64) void gemm_nt(
    const short* __restrict__ A, const short* __restrict__ B,
    int Mdim, int Ndim, int Kdim,
    const float* __restrict__ nb, const float* __restrict__ na,
    const float* __restrict__ invSum, const float* __restrict__ PulT,
    short* __restrict__ obf, float* __restrict__ of32) {
  constexpr int WROWS = WAVES / 2;
  constexpr int MF = BM / WROWS / 16;
  constexpr int NF = BN / 32;
  constexpr int CH = BK / 8;
  constexpr int CMSK = CH - 1;
  constexpr int RG = 512 / BK;
  constexpr int AL = BM / RG / WAVES;
  constexpr int BL = BN / RG / WAVES;
  constexpr int VM = ((BM + BN) * BK * 2) / (WAVES * 64 * 16);
  __shared__ short tA[2][BM * BK];
  __shared__ short tB[2][BN * BK];
  const int ntn = Ndim / BN;
  const int bid = blockIdx.x;
  const int tm = bid / ntn;
  const int tn = bid % ntn;
  const int tid = threadIdx.x;
  const int wave = tid >> 6;
  const int lane = tid & 63;
  const int wrow = (wave >> 1) * (BM / WROWS);
  const int wcol = (wave & 1) * (BN / 2);
  const int lrow = lane & 15;
  const int lkb = lane >> 4;

  f4_t acc[MF][NF];
#pragma unroll
  for (int m = 0; m < MF; ++m)
#pragma unroll
    for (int n = 0; n < NF; ++n) acc[m][n] = (f4_t)(0.f);

  const int srow = lane / CH;
  const int schunk = (lane & CMSK) ^ (srow & CMSK);
  const size_t arow0 = (size_t)tm * BM;
  const size_t brow0 = (size_t)tn * BN;

  auto stageA = [&](int buf, int k0) {
#pragma unroll
    for (int i = 0; i < AL; ++i) {
      const int li = i * WAVES + wave;
      const int row = li * RG + srow;
      gload_lds16(A + (arow0 + row) * Kdim + k0 + schunk * 8,
                  &tA[buf][li * 512]);
    }
  };
  auto stageB = [&](int buf, int k0) {
#pragma unroll
    for (int i = 0; i < BL; ++i) {
      const int li = i * WAVES + wave;
      const int row = li * RG + srow;
      gload_lds16(B + (brow0 + row) * Kdim + k0 + schunk * 8,
                  &tB[buf][li * 512]);
    }
  };
  auto compute = [&](int buf) {
#pragma unroll
    for (int kk = 0; kk < BK / 32; ++kk) {
      bf8_t af[MF], bfv[NF];
#pragma unroll
      for (int m = 0; m < MF; ++m) {
        const int row = wrow + m * 16 + lrow;
        const int ch = ((kk * 4 + lkb) & CMSK) ^ (row & CMSK);
        af[m] = *reinterpret_cast<const bf8_t*>(&tA[buf][row * BK + ch * 8]);
      }
#pragma unroll
      for (int n = 0; n < NF; ++n) {
        const int row = wcol + n * 16 + lrow;
        const int ch = ((kk * 4 + lkb) & CMSK) ^ (row & CMSK);
        bfv[n] = *reinterpret_cast<const bf8_t*>(&tB[buf][row * BK + ch * 8]);
      }
#pragma unroll
      for (int m = 0; m < MF; ++m)
#pragma unroll
        for (int n = 0; n < NF; ++n)
          acc[m][n] = __builtin_amdgcn_mfma_f32_16x16x32_bf16(af[m], bfv[n],
                                                              acc[m][n], 0, 0, 0);
    }
  };

  const int Kchunk = Kdim / SPLITK;
  const int kbase = blockIdx.y * Kchunk;
  const int NT = Kchunk / BK;
  stageA(0, kbase);
  stageB(0, kbase);
  stageA(1, kbase + BK);
  stageB(1, kbase + BK);
  for (int t = 0; t < NT; ++t) {
    const int cur = t & 1;
    if (t < NT - 1) {
      if constexpr (VM == 6)
        asm volatile("s_waitcnt vmcnt(6)" ::: "memory");
      else if constexpr (VM == 3)
        asm volatile("s_waitcnt vmcnt(3)" ::: "memory");
      else
        asm volatile("s_waitcnt vmcnt(0)" ::: "memory");
    } else {
      asm volatile("s_waitcnt vmcnt(0)" ::: "memory");
    }
    __builtin_amdgcn_s_barrier();
    __builtin_amdgcn_sched_barrier(0);
    compute(cur);
    __builtin_amdgcn_s_barrier();
    __builtin_amdgcn_sched_barrier(0);
    if (t + 2 < NT) {
      stageA(cur, kbase + (t + 2) * BK);
      stageB(cur, kbase + (t + 2) * BK);
    }
  }

  const size_t poff = (size_t)blockIdx.y * Mdim * Ndim;
#pragma unroll
  for (int m = 0; m < MF; ++m) {
    const int gr0 = tm * BM + wrow + m * 16 + lkb * 4;
#pragma unroll
    for (int n = 0; n < NF; ++n) {
      const int gcol = tn * BN + wcol + n * 16 + lrow;
#pragma unroll
      for (int r = 0; r < 4; ++r) {
        const int gr = gr0 + r;
        const float v = acc[m][n][r];
        if (EPI == 1) {
          float t = fmaxf(nb[gr] - 2.f * v + na[gcol], 0.f);
          of32[(size_t)gr * Ndim + gcol] = __expf(-DPc * sqrtf(t));
        } else if (EPI == 2) {
          float y = v * invSum[gcol] + PulT[(size_t)gr * Ndim + gcol];
          if (FINAL) of32[(size_t)gcol * Mdim + gr] = fmaxf(y, 0.f);
          else       obf[(size_t)gr * Ndim + gcol] = f2bf(y);
        } else {  // EPI 8: raw split-K partial
          of32[poff + (size_t)gr * Ndim + gcol] = v;
        }
      }
    }
  }
}

// invS[i] = 1/(sumTul_i + sumTuu_i); rs[i] = sumTuu_i*invS[i].
__global__ void rowsum_inv(const float* __restrict__ Tul,
                           const float* __restrict__ prow,
                           float* __restrict__ invS, float* __restrict__ rs,
                           int n, int m) {
  const int i = blockIdx.x;
  const int tid = threadIdx.x;
  const float* tr = Tul + (size_t)i * m;
  float sl = 0.f, su = 0.f;
  for (int c = tid * 4; c < m; c += 1024) {
    float4 v = *reinterpret_cast<const float4*>(tr + c);
    sl += v.x + v.y + v.z + v.w;
  }
  if (tid < 32) su = prow[(size_t)tid * n + i];
#pragma unroll
  for (int off = 32; off > 0; off >>= 1) {
    sl += __shfl_down(sl, off);
    su += __shfl_down(su, off);
  }
  __shared__ float wl[4], wu[4];
  if ((tid & 63) == 0) { wl[tid >> 6] = sl; wu[tid >> 6] = su; }
  __syncthreads();
  if (tid == 0) {
    const float l = wl[0] + wl[1] + wl[2] + wl[3];
    const float u = wu[0] + wu[1] + wu[2] + wu[3];
    const float iv = 1.f / (l + u);
    invS[i] = iv;
    rs[i] = u * iv;
  }
}

// Perron Rayleigh partials, restricted to rows 0..NS-1.
__global__ __launch_bounds__(256) void pmatvec_dot(
    const short* __restrict__ Tuu, const float* __restrict__ rs,
    const float* __restrict__ invS, float* __restrict__ pd, int n, int NS) {
  const int i = blockIdx.x;
  const int tid = threadIdx.x;
  const short* ur = Tuu + (size_t)i * n;
  float s = 0.f;
  for (int c = tid * 8; c < n; c += 2048) {
    bf8_t v = *reinterpret_cast<const bf8_t*>(ur + c);
#pragma unroll
    for (int j = 0; j < 8; ++j) s += bf2f(v[j]) * rs[c + j];
  }
#pragma unroll
  for (int off = 32; off > 0; off >>= 1) s += __shfl_down(s, off);
  __shared__ float wsum[4];
  if ((tid & 63) == 0) wsum[tid >> 6] = s;
  __syncthreads();
  if (tid == 0) {
    const float y = (wsum[0] + wsum[1] + wsum[2] + wsum[3]) * invS[i];
    pd[i] = y * rs[i];
    pd[NS + i] = rs[i] * rs[i];
  }
}

// Stage 2: lamf[0] = lam/(1-lam), lam = S1/S2 clamped.
__global__ __launch_bounds__(256) void dot_stage2(
    const float* __restrict__ pd, int nblk, float* __restrict__ lamf) {
  const int tid = threadIdx.x;
  float s1 = 0.f, s2 = 0.f;
  for (int i = tid; i < nblk; i += 256) {
    s1 += pd[i];
    s2 += pd[nblk + i];
  }
#pragma unroll
  for (int off = 32; off > 0; off >>= 1) {
    s1 += __shfl_down(s1, off);
    s2 += __shfl_down(s2, off);
  }
  __shared__ float w1[4], w2[4];
  if ((tid & 63) == 0) { w1[tid >> 6] = s1; w2[tid >> 6] = s2; }
  __syncthreads();
  if (tid == 0) {
    const float S1 = w1[0] + w1[1] + w1[2] + w1[3];
    const float S2 = w2[0] + w2[1] + w2[2] + w2[3];
    float lam = (S2 > 0.f) ? (S1 / S2) : 0.8f;
    lam = fminf(fmaxf(lam, 0.05f), 0.95f);
    lamf[0] = lam / (1.f - lam);
  }
}

// Fused m=1 finish, bT-free:
//   w = (1+f) * parts_sum * invS[i]  (loop A, LDS-transposed)
//   out[i][l] = max(w + Tul[i][l]*invS[i], 0)  (loop B; Tul aliases out —
//   each element read-then-written by the SAME thread, safe).
template <int PARTS>
__global__ __launch_bounds__(256) void reduce_final1(
    const float* __restrict__ parts, const float* __restrict__ Tul,
    const float* __restrict__ invS, const float* __restrict__ lamf,
    float* __restrict__ out, int Mdim, int Ndim) {
  __shared__ float t[64][65];
  const size_t tot = (size_t)Mdim * Ndim;
  const int ntj = Ndim / 64;
  const int ti = blockIdx.x / ntj;   // l-tile
  const int tj = blockIdx.x % ntj;   // i-tile
  const int i0 = ti * 64, j0 = tj * 64;
  const int tid = threadIdx.x;
  const float f1 = 1.f + lamf[0];
  for (int e = tid; e < 64 * 64; e += 256) {
    const int r = e >> 6, c = e & 63;  // r=l, c=i (coalesced over i)
    const size_t idx = (size_t)(i0 + r) * Ndim + j0 + c;
    float v = parts[idx];
#pragma unroll
    for (int s = 1; s < PARTS; ++s) v += parts[(size_t)s * tot + idx];
    t[r][c] = f1 * v * invS[j0 + c];
  }
  __syncthreads();
  for (int e = tid; e < 64 * 64; e += 256) {
    const int c = e >> 6, r = e & 63;  // c=i, r=l (coalesced over l)
    const size_t o = (size_t)(j0 + c) * Mdim + i0 + r;
    const float b = Tul[o] * invS[j0 + c];
    out[o] = fmaxf(t[r][c] + b, 0.f);
  }
}

// Z0[l][i] = bf16(Tul[i][l]*invS[i]); WB also writes f32 PulT (fallback only).
template <bool WB>
__global__ void make_z0(const float* __restrict__ Tul,
                        const float* __restrict__ invS,
                        float* __restrict__ PulT, short* __restrict__ Z0,
                        int n, int m) {
  __shared__ float t[64][65];
  const int ntj = m / 64;
  const int ti = blockIdx.x / ntj;
  const int tj = blockIdx.x % ntj;
  const int i0 = ti * 64, j0 = tj * 64;
  const int tid = threadIdx.x;
  for (int e = tid; e < 64 * 64; e += 256) {
    const int r = e >> 6, c = e & 63;
    t[r][c] = Tul[(size_t)(i0 + r) * m + j0 + c];
  }
  __syncthreads();
  for (int e = tid; e < 64 * 64; e += 256) {
    const int jr = e >> 6, ir = e & 63;
    const float p = t[ir][jr] * invS[i0 + ir];
    if (WB) PulT[(size_t)(j0 + jr) * n + i0 + ir] = p;
    Z0[(size_t)(j0 + jr) * n + i0 + ir] = f2bf(p);
  }
}

extern "C" void kernel_launch(void* const* d_in, const int* in_sizes, int n_in,
                              void* d_out, int out_size, void* d_ws, size_t ws_size,
                              hipStream_t stream) {
  const float* x = (const float*)d_in[0];
  const float* kn = (const float*)d_in[1];
  float* out = (float*)d_out;
  const int N = 4096, D = 1024, M = 512;
  const int NS = 1024;  // Rayleigh subset rows

  char* ws = (char*)d_ws;
  short* xb = (short*)ws;    ws += (size_t)N * D * 2;   // 8.4 MB
  short* kb = (short*)ws;    ws += (size_t)M * D * 2;   // 1.0 MB
  char* xq = ws;             ws += (size_t)N * D;       // 4.2 MB fp8 x (linear)
  short* T = (short*)ws;     ws += (size_t)N * N * 2;   // 33.5 MB (Tuu bf16)
  short* Z0 = (short*)ws;    ws += (size_t)M * N * 2;   // 4.2 MB
  short* Z1 = (short*)ws;    ws += (size_t)M * N * 2;   // 4.2 MB (fallback only)
  float* nb = (float*)ws;    ws += (size_t)N * 4;
  float* na = (float*)ws;    ws += (size_t)M * 4;
  float* invS = (float*)ws;  ws += (size_t)N * 4;
  float* rs = (float*)ws;    ws += (size_t)N * 4;
  float* lamf = (float*)ws;  ws += 64;
  float* pd = (float*)ws;    ws += 2 * 4096 * 4;
  float* prow = (float*)ws;  ws += (size_t)32 * N * 4;  // 512 KB col-partials
  float* parts = (float*)ws; ws += (size_t)M * N * 4 * 2;  // 16.8 MB splitK=2
  const size_t NEED = (size_t)(ws - (char*)d_ws);
  const bool EXT = ws_size >= NEED;
  float* bT = parts;  // fallback-only PulT aliases the (then-unused) parts
  float* Tul = out;   // d_out doubles as Tul scratch (overwritten at the end)

  prep_rows_all<<<N + M, 256, 0, stream>>>(x, kn, D, N, xb, kb, xq, nb, na);

  // Tul[i][l] = exp(-dp*sqrt(max(nb_i - 2 x.k + na_l, 0)))   [4096 x 512] f32
  gemm_nt<4, 1, false, 1, 128, 64, 64><<<(N / 128) * (M / 64), 256, 0, stream>>>(
      xb, kb, N, M, D, nb, na, nullptr, nullptr, nullptr, Tul);
  // T[i][j] = exp(-dp*sqrt(max(2nb_i - 2 x.x, 0))), diag 0  (128^2 2-phase,
  // MX-scaled fp8 32x32x64, 2 blocks/CU; emits prow row-sum partials).
  gemm_nt8_tuu<<<(N / 128) * (N / 128), 256, 0, stream>>>(
      xq, N, D, nb, T, prow);

  rowsum_inv<<<N, 256, 0, stream>>>(Tul, prow, invS, rs, N, M);

  if (EXT) {
    make_z0<false><<<(N / 64) * (M / 64), 256, 0, stream>>>(
        Tul, invS, nullptr, Z0, N, M);
    // Single P-application + one-mode Richardson extrapolation:
    //   z1 = b P^T + b;  out = (1+f)*z1raw*invS + b,  f = lam/(1-lam),
    // lam = Rayleigh quotient with s = Puu*1 restricted to NS rows.
    pmatvec_dot<<<NS, 256, 0, stream>>>(T, rs, invS, pd, N, NS);
    dot_stage2<<<1, 256, 0, stream>>>(pd, NS, lamf);
    const dim3 sg((M / 128) * (N / 64), 2);  // (256, 2)
    gemm_nt<8, 8, false, 2, 128, 64, 64><<<sg, 512, 0, stream>>>(
        Z0, T, M, N, N, nullptr, nullptr, nullptr, nullptr, nullptr, parts);
    reduce_final1<2><<<(M / 64) * (N / 64), 256, 0, stream>>>(
        parts, Tul, invS, lamf, out, M, N);
  } else {
    make_z0<true><<<(N / 64) * (M / 64), 256, 0, stream>>>(
        Tul, invS, bT, Z0, N, M);
    // fallback: plain Jacobi, 34 iterations
    short* cur = Z0;
    short* nxt = Z1;
    const int NITER = 34;
    for (int it = 0; it < NITER; ++it) {
      if (it == NITER - 1) {
        gemm_nt<8, 2, true, 1, 128, 64, 64>
            <<<(M / 128) * (N / 64), 512, 0, stream>>>(
                cur, T, M, N, N, nullptr, nullptr, invS, bT, nullptr, out);
      } else {
        gemm_nt<8, 2, false, 1, 128, 64, 64>
            <<<(M / 128) * (N / 64), 512, 0, stream>>>(
                cur, T, M, N, N, nullptr, nullptr, invS, bT, nxt, nullptr);
      }
      short* t2 = cur; cur = nxt; nxt = t2;
    }
  }
}

// Round 4
// 121.427 us; speedup vs baseline: 1.0183x; 1.0183x over previous
//
#include <hip/hip_runtime.h>
#include <hip/hip_bf16.h>
#include <cstdint>
#include <cstddef>

#define DPc 0.05f

typedef __attribute__((ext_vector_type(8))) short bf8_t;   // 8 bf16
typedef __attribute__((ext_vector_type(4))) float f4_t;    // 4 fp32 acc
typedef long i64;
typedef __attribute__((ext_vector_type(2))) long i64x2;
typedef __attribute__((ext_vector_type(4))) int i32x4;
typedef __attribute__((ext_vector_type(8))) int i32x8;
typedef __attribute__((ext_vector_type(16))) float f32x16;

__device__ __forceinline__ short f2bf(float x) {
  __hip_bfloat16 h = __float2bfloat16(x);
  return *reinterpret_cast<short*>(&h);
}
__device__ __forceinline__ float bf2f(short x) {
  __hip_bfloat16 h;
  *reinterpret_cast<short*>(&h) = x;
  return __bfloat162float(h);
}

__device__ __forceinline__ void gload_lds16(const void* g, void* l) {
  __builtin_amdgcn_global_load_lds(
      (const __attribute__((address_space(1))) unsigned int*)g,
      (__attribute__((address_space(3))) unsigned int*)l,
      16, 0, 0);
}

// Per-row: f32 sum of squares + bf16 cast; x rows also emit a PLAIN row-major
// fp8-e4m3 copy (the MX-scaled 32x32x64 MFMA consumes per-lane-contiguous
// 32-byte K blocks).
__global__ void prep_rows_all(const float* __restrict__ X,
                              const float* __restrict__ Kn, int D, int N,
                              short* __restrict__ Xb, short* __restrict__ Kb,
                              char* __restrict__ Xq,
                              float* __restrict__ nb, float* __restrict__ na) {
  const int row = blockIdx.x;
  const int tid = threadIdx.x;
  const float* xr;
  short* br;
  char* qr = nullptr;
  float* nrm;
  if (row < N) {
    xr = X + (size_t)row * D;
    br = Xb + (size_t)row * D;
    qr = Xq + (size_t)row * D;
    nrm = nb + row;
  } else {
    const int r2 = row - N;
    xr = Kn + (size_t)r2 * D;
    br = Kb + (size_t)r2 * D;
    nrm = na + r2;
  }
  float s = 0.f;
  for (int c = tid * 4; c < D; c += 256 * 4) {
    const float4 v = *reinterpret_cast<const float4*>(xr + c);
    s += v.x * v.x + v.y * v.y + v.z * v.z + v.w * v.w;
    short4 b;
    b.x = f2bf(v.x); b.y = f2bf(v.y); b.z = f2bf(v.z); b.w = f2bf(v.w);
    *reinterpret_cast<short4*>(br + c) = b;
    if (qr) {
      int p = __builtin_amdgcn_cvt_pk_fp8_f32(v.x, v.y, 0, false);
      p = __builtin_amdgcn_cvt_pk_fp8_f32(v.z, v.w, p, true);
      *reinterpret_cast<int*>(qr + c) = p;
    }
  }
#pragma unroll
  for (int off = 32; off > 0; off >>= 1) s += __shfl_down(s, off);
  __shared__ float wsum[4];
  if ((tid & 63) == 0) wsum[tid >> 6] = s;
  __syncthreads();
  if (tid == 0) *nrm = wsum[0] + wsum[1] + wsum[2] + wsum[3];
}

// ------------- 128x128-tile 2-phase NT GEMM (Tuu, MX-fp8, 8 waves) ----------
// Occupancy experiment: identical tile/LDS/swizzle/schedule to the 4-wave
// version, but 512 threads -> 2 blocks/CU x 8 waves = 4 waves/SIMD (all
// previous variants had exactly 2 waves/SIMD and all landed ~50us with every
// pipe ~80% idle -> latency-bound, occupancy is the untested lever).
// Per wave: 64x32 output (acc 2x1 of 32x32), 12 ds_read_b128, 4 MFMAs,
// 4 gloads per K-tile.  True double-buffer, 1-tile lead, single vmcnt(0) +
// barrier pair per K-tile.
__global__ __launch_bounds__(512, 4) void gemm_nt8_tuu(
    const char* __restrict__ Aq, int Ndim, int KB,
    const float* __restrict__ nb, short* __restrict__ obf,
    float* __restrict__ prow) {
  __shared__ char tA[2][128 * 128];
  __shared__ char tB[2][128 * 128];
  const int ntn = Ndim / 128;
  const int tm = blockIdx.x / ntn;
  const int tn = blockIdx.x % ntn;
  const int tid = threadIdx.x;
  const int wave = tid >> 6;   // 0..7
  const int lane = tid & 63;
  const int wm = wave >> 2;    // 0..1  (64-row block)
  const int wn = wave & 3;     // 0..3  (32-col block)
  const int l31 = lane & 31;
  const int lh = lane >> 5;    // 0..1  (K-half within a 64-elem block)

  f32x16 acc[2];
#pragma unroll
  for (int m = 0; m < 2; ++m) acc[m] = (f32x16)(0.f);

  const int srow = lane >> 3;          // 0..7
  const int sch = (lane & 7) ^ srow;   // pre-swizzled source 16B chunk
  const size_t arow0 = (size_t)tm * 128;
  const size_t brow0 = (size_t)tn * 128;

  // grp: 0 = A/mf0 rows, 1 = A/mf1 rows, 2 = B even-32 rows, 3 = B odd-32.
  // Each grp = 64 rows; 8 waves x 1 gload (8 rows each).
  auto stage = [&](int buf, int k0B, int grp) {
    const int lin = wave * 8;                                // 0..56
    const int row0 = ((lin >> 5) * 64) + (lin & 31) + ((grp & 1) * 32);
    const size_t base = (grp < 2) ? arow0 : brow0;
    char* dst = (grp < 2) ? &tA[buf][row0 * 128] : &tB[buf][row0 * 128];
    gload_lds16(Aq + (base + row0 + srow) * KB + k0B + sch * 16, dst);
  };

  // Read-side swizzled chunk byte-offsets: chunk (q*4 + lh*2 + h) ^ (row&7).
  // row = 32*frag + l31 with 32|base => row&7 == l31&7 (lane-constant).
  int coff[2][2];
#pragma unroll
  for (int q = 0; q < 2; ++q)
#pragma unroll
    for (int h = 0; h < 2; ++h)
      coff[q][h] = (((q * 4 + lh * 2 + h) ^ (l31 & 7)) << 4);
  const int aoff = (wm * 64 + l31) * 128;
  const int boff = (wn * 32 + l31) * 128;

  auto rdA = [&](int buf, int mf, int q) -> i32x8 {
    const char* p = &tA[buf][aoff + mf * 32 * 128];
    const i32x4 lo = *reinterpret_cast<const i32x4*>(p + coff[q][0]);
    const i32x4 hi = *reinterpret_cast<const i32x4*>(p + coff[q][1]);
    i32x8 r;
    r[0] = lo[0]; r[1] = lo[1]; r[2] = lo[2]; r[3] = lo[3];
    r[4] = hi[0]; r[5] = hi[1]; r[6] = hi[2]; r[7] = hi[3];
    return r;
  };
  auto rdB = [&](int buf, int q) -> i32x8 {
    const char* p = &tB[buf][boff];
    const i32x4 lo = *reinterpret_cast<const i32x4*>(p + coff[q][0]);
    const i32x4 hi = *reinterpret_cast<const i32x4*>(p + coff[q][1]);
    i32x8 r;
    r[0] = lo[0]; r[1] = lo[1]; r[2] = lo[2]; r[3] = lo[3];
    r[4] = hi[0]; r[5] = hi[1]; r[6] = hi[2]; r[7] = hi[3];
    return r;
  };

#define MFMA_SC(A_, B_, C_)                                        \
  __builtin_amdgcn_mfma_scale_f32_32x32x64_f8f6f4(                 \
      (A_), (B_), (C_), 0, 0, 0, 0x7F7F7F7F, 0, 0x7F7F7F7F)

  const int NK = KB / 128;  // 8
#pragma unroll
  for (int g = 0; g < 4; ++g) stage(0, 0, g);
  asm volatile("s_waitcnt vmcnt(0)" ::: "memory");
  __builtin_amdgcn_s_barrier();
  __builtin_amdgcn_sched_barrier(0);

  for (int t = 0; t < NK; ++t) {
    const int cur = t & 1;
    // Prefetch tile t+1 into the NON-read buffer at the top of tile t.
    if (t + 1 < NK) {
#pragma unroll
      for (int g = 0; g < 4; ++g) stage(cur ^ 1, (t + 1) * 128, g);
    }
    __builtin_amdgcn_sched_barrier(0);
    // One unfenced region: 12 ds_read_b128 + 4 MFMAs.
    i32x8 a00 = rdA(cur, 0, 0), a01 = rdA(cur, 0, 1);
    i32x8 a10 = rdA(cur, 1, 0), a11 = rdA(cur, 1, 1);
    i32x8 b00 = rdB(cur, 0), b01 = rdB(cur, 1);
    __builtin_amdgcn_s_setprio(1);
    acc[0] = MFMA_SC(a00, b00, acc[0]);
    acc[1] = MFMA_SC(a10, b00, acc[1]);
    acc[0] = MFMA_SC(a01, b01, acc[0]);
    acc[1] = MFMA_SC(a11, b01, acc[1]);
    __builtin_amdgcn_s_setprio(0);
    // Next iteration reads buf^1: its loads must have landed.
    asm volatile("s_waitcnt vmcnt(0)" ::: "memory");
    __builtin_amdgcn_s_barrier();
    __builtin_amdgcn_sched_barrier(0);
  }
#undef MFMA_SC

  // Epilogue: 32x32 C layout: col = l31, row = (r&3) + 8*(r>>2) + 4*lh.
  float* lrs = reinterpret_cast<float*>(tA);  // dead LDS: [128 rows][4 wn]
#pragma unroll
  for (int mf = 0; mf < 2; ++mf) {
    float rsum[16];
    const int gcol = tn * 128 + wn * 32 + l31;
#pragma unroll
    for (int r = 0; r < 16; ++r) {
      const int lr = (r & 3) + 8 * (r >> 2) + 4 * lh;
      const int gr = tm * 128 + wm * 64 + mf * 32 + lr;
      const float v = acc[mf][r];
      const float tt = fmaxf(2.f * nb[gr] - 2.f * v, 0.f);
      float e = __expf(-DPc * sqrtf(tt));
      if (gr == gcol) e = 0.f;
      rsum[r] = e;
      obf[(size_t)gr * Ndim + gcol] = f2bf(e);
    }
#pragma unroll
    for (int r = 0; r < 16; ++r) {
      float v = rsum[r];
      v += __shfl_xor(v, 1);
      v += __shfl_xor(v, 2);
      v += __shfl_xor(v, 4);
      v += __shfl_xor(v, 8);
      v += __shfl_xor(v, 16);
      if (l31 == 0) {
        const int lr = (r & 3) + 8 * (r >> 2) + 4 * lh;
        lrs[(wm * 64 + mf * 32 + lr) * 4 + wn] = v;
      }
    }
  }
  __syncthreads();
  if (tid < 128) {
    const float s = lrs[tid * 4 + 0] + lrs[tid * 4 + 1] +
                    lrs[tid * 4 + 2] + lrs[tid * 4 + 3];
    prow[(size_t)tn * Ndim + tm * 128 + tid] = s;
  }
}

// ---------------- BMxBN-tile NT GEMM (Tul + P-application) ------------------
// EPI 1: Tul f32 = __expf(-dp*sqrt(max(nb_i-2v+na_j,0))).
// EPI 2: y = v*invS[gcol]+PulT (fallback); FINAL ? out^T f32 : Z bf16.
// EPI 8: of32[split-partial] = v.
template <int WAVES, int EPI, bool FINAL, int SPLITK, int BM, int BN, int BK>
__global__ __launch_bounds__(WAVES * 64) void gemm_nt(
    const short* __restrict__ A, const short* __restrict__ B,
    int Mdim, int Ndim, int Kdim,
    const float* __restrict__ nb, const float* __restrict__ na,
    const float* __restrict__ invSum, const float* __restrict__ PulT,
    short* __restrict__ obf, float* __restrict__ of32) {
  constexpr int WROWS = WAVES / 2;
  constexpr int MF = BM / WROWS / 16;
  constexpr int NF = BN / 32;
  constexpr int CH = BK / 8;
  constexpr int CMSK = CH - 1;
  constexpr int RG = 512 / BK;
  constexpr int AL = BM / RG / WAVES;
  constexpr int BL = BN / RG / WAVES;
  constexpr int VM = ((BM + BN) * BK * 2) / (WAVES * 64 * 16);
  __shared__ short tA[2][BM * BK];
  __shared__ short tB[2][BN * BK];
  const int ntn = Ndim / BN;
  const int bid = blockIdx.x;
  const int tm = bid / ntn;
  const int tn = bid % ntn;
  const int tid = threadIdx.x;
  const int wave = tid >> 6;
  const int lane = tid & 63;
  const int wrow = (wave >> 1) * (BM / WROWS);
  const int wcol = (wave & 1) * (BN / 2);
  const int lrow = lane & 15;
  const int lkb = lane >> 4;

  f4_t acc[MF][NF];
#pragma unroll
  for (int m = 0; m < MF; ++m)
#pragma unroll
    for (int n = 0; n < NF; ++n) acc[m][n] = (f4_t)(0.f);

  const int srow = lane / CH;
  const int schunk = (lane & CMSK) ^ (srow & CMSK);
  const size_t arow0 = (size_t)tm * BM;
  const size_t brow0 = (size_t)tn * BN;

  auto stageA = [&](int buf, int k0) {
#pragma unroll
    for (int i = 0; i < AL; ++i) {
      const int li = i * WAVES + wave;
      const int row = li * RG + srow;
      gload_lds16(A + (arow0 + row) * Kdim + k0 + schunk * 8,
                  &tA[buf][li * 512]);
    }
  };
  auto stageB = [&](int buf, int k0) {
#pragma unroll
    for (int i = 0; i < BL; ++i) {
      const int li = i * WAVES + wave;
      const int row = li * RG + srow;
      gload_lds16(B + (brow0 + row) * Kdim + k0 + schunk * 8,
                  &tB[buf][li * 512]);
    }
  };
  auto compute = [&](int buf) {
#pragma unroll
    for (int kk = 0; kk < BK / 32; ++kk) {
      bf8_t af[MF], bfv[NF];
#pragma unroll
      for (int m = 0; m < MF; ++m) {
        const int row = wrow + m * 16 + lrow;
        const int ch = ((kk * 4 + lkb) & CMSK) ^ (row & CMSK);
        af[m] = *reinterpret_cast<const bf8_t*>(&tA[buf][row * BK + ch * 8]);
      }
#pragma unroll
      for (int n = 0; n < NF; ++n) {
        const int row = wcol + n * 16 + lrow;
        const int ch = ((kk * 4 + lkb) & CMSK) ^ (row & CMSK);
        bfv[n] = *reinterpret_cast<const bf8_t*>(&tB[buf][row * BK + ch * 8]);
      }
#pragma unroll
      for (int m = 0; m < MF; ++m)
#pragma unroll
        for (int n = 0; n < NF; ++n)
          acc[m][n] = __builtin_amdgcn_mfma_f32_16x16x32_bf16(af[m], bfv[n],
                                                              acc[m][n], 0, 0, 0);
    }
  };

  const int Kchunk = Kdim / SPLITK;
  const int kbase = blockIdx.y * Kchunk;
  const int NT = Kchunk / BK;
  stageA(0, kbase);
  stageB(0, kbase);
  stageA(1, kbase + BK);
  stageB(1, kbase + BK);
  for (int t = 0; t < NT; ++t) {
    const int cur = t & 1;
    if (t < NT - 1) {
      if constexpr (VM == 6)
        asm volatile("s_waitcnt vmcnt(6)" ::: "memory");
      else if constexpr (VM == 3)
        asm volatile("s_waitcnt vmcnt(3)" ::: "memory");
      else
        asm volatile("s_waitcnt vmcnt(0)" ::: "memory");
    } else {
      asm volatile("s_waitcnt vmcnt(0)" ::: "memory");
    }
    __builtin_amdgcn_s_barrier();
    __builtin_amdgcn_sched_barrier(0);
    compute(cur);
    __builtin_amdgcn_s_barrier();
    __builtin_amdgcn_sched_barrier(0);
    if (t + 2 < NT) {
      stageA(cur, kbase + (t + 2) * BK);
      stageB(cur, kbase + (t + 2) * BK);
    }
  }

  const size_t poff = (size_t)blockIdx.y * Mdim * Ndim;
#pragma unroll
  for (int m = 0; m < MF; ++m) {
    const int gr0 = tm * BM + wrow + m * 16 + lkb * 4;
#pragma unroll
    for (int n = 0; n < NF; ++n) {
      const int gcol = tn * BN + wcol + n * 16 + lrow;
#pragma unroll
      for (int r = 0; r < 4; ++r) {
        const int gr = gr0 + r;
        const float v = acc[m][n][r];
        if (EPI == 1) {
          float t = fmaxf(nb[gr] - 2.f * v + na[gcol], 0.f);
          of32[(size_t)gr * Ndim + gcol] = __expf(-DPc * sqrtf(t));
        } else if (EPI == 2) {
          float y = v * invSum[gcol] + PulT[(size_t)gr * Ndim + gcol];
          if (FINAL) of32[(size_t)gcol * Mdim + gr] = fmaxf(y, 0.f);
          else       obf[(size_t)gr * Ndim + gcol] = f2bf(y);
        } else {  // EPI 8: raw split-K partial
          of32[poff + (size_t)gr * Ndim + gcol] = v;
        }
      }
    }
  }
}

// invS[i] = 1/(sumTul_i + sumTuu_i); rs[i] = sumTuu_i*invS[i].
__global__ void rowsum_inv(const float* __restrict__ Tul,
                           const float* __restrict__ prow,
                           float* __restrict__ invS, float* __restrict__ rs,
                           int n, int m) {
  const int i = blockIdx.x;
  const int tid = threadIdx.x;
  const float* tr = Tul + (size_t)i * m;
  float sl = 0.f, su = 0.f;
  for (int c = tid * 4; c < m; c += 1024) {
    float4 v = *reinterpret_cast<const float4*>(tr + c);
    sl += v.x + v.y + v.z + v.w;
  }
  if (tid < 32) su = prow[(size_t)tid * n + i];
#pragma unroll
  for (int off = 32; off > 0; off >>= 1) {
    sl += __shfl_down(sl, off);
    su += __shfl_down(su, off);
  }
  __shared__ float wl[4], wu[4];
  if ((tid & 63) == 0) { wl[tid >> 6] = sl; wu[tid >> 6] = su; }
  __syncthreads();
  if (tid == 0) {
    const float l = wl[0] + wl[1] + wl[2] + wl[3];
    const float u = wu[0] + wu[1] + wu[2] + wu[3];
    const float iv = 1.f / (l + u);
    invS[i] = iv;
    rs[i] = u * iv;
  }
}

// Perron Rayleigh partials, restricted to rows 0..NS-1.
__global__ __launch_bounds__(256) void pmatvec_dot(
    const short* __restrict__ Tuu, const float* __restrict__ rs,
    const float* __restrict__ invS, float* __restrict__ pd, int n, int NS) {
  const int i = blockIdx.x;
  const int tid = threadIdx.x;
  const short* ur = Tuu + (size_t)i * n;
  float s = 0.f;
  for (int c = tid * 8; c < n; c += 2048) {
    bf8_t v = *reinterpret_cast<const bf8_t*>(ur + c);
#pragma unroll
    for (int j = 0; j < 8; ++j) s += bf2f(v[j]) * rs[c + j];
  }
#pragma unroll
  for (int off = 32; off > 0; off >>= 1) s += __shfl_down(s, off);
  __shared__ float wsum[4];
  if ((tid & 63) == 0) wsum[tid >> 6] = s;
  __syncthreads();
  if (tid == 0) {
    const float y = (wsum[0] + wsum[1] + wsum[2] + wsum[3]) * invS[i];
    pd[i] = y * rs[i];
    pd[NS + i] = rs[i] * rs[i];
  }
}

// Stage 2: lamf[0] = lam/(1-lam), lam = S1/S2 clamped.
__global__ __launch_bounds__(256) void dot_stage2(
    const float* __restrict__ pd, int nblk, float* __restrict__ lamf) {
  const int tid = threadIdx.x;
  float s1 = 0.f, s2 = 0.f;
  for (int i = tid; i < nblk; i += 256) {
    s1 += pd[i];
    s2 += pd[nblk + i];
  }
#pragma unroll
  for (int off = 32; off > 0; off >>= 1) {
    s1 += __shfl_down(s1, off);
    s2 += __shfl_down(s2, off);
  }
  __shared__ float w1[4], w2[4];
  if ((tid & 63) == 0) { w1[tid >> 6] = s1; w2[tid >> 6] = s2; }
  __syncthreads();
  if (tid == 0) {
    const float S1 = w1[0] + w1[1] + w1[2] + w1[3];
    const float S2 = w2[0] + w2[1] + w2[2] + w2[3];
    float lam = (S2 > 0.f) ? (S1 / S2) : 0.8f;
    lam = fminf(fmaxf(lam, 0.05f), 0.95f);
    lamf[0] = lam / (1.f - lam);
  }
}

// Fused m=1 finish, bT-free:
//   w = (1+f) * parts_sum * invS[i]  (loop A, LDS-transposed)
//   out[i][l] = max(w + Tul[i][l]*invS[i], 0)  (loop B; Tul aliases out —
//   each element read-then-written by the SAME thread, safe).
template <int PARTS>
__global__ __launch_bounds__(256) void reduce_final1(
    const float* __restrict__ parts, const float* __restrict__ Tul,
    const float* __restrict__ invS, const float* __restrict__ lamf,
    float* __restrict__ out, int Mdim, int Ndim) {
  __shared__ float t[64][65];
  const size_t tot = (size_t)Mdim * Ndim;
  const int ntj = Ndim / 64;
  const int ti = blockIdx.x / ntj;   // l-tile
  const int tj = blockIdx.x % ntj;   // i-tile
  const int i0 = ti * 64, j0 = tj * 64;
  const int tid = threadIdx.x;
  const float f1 = 1.f + lamf[0];
  for (int e = tid; e < 64 * 64; e += 256) {
    const int r = e >> 6, c = e & 63;  // r=l, c=i (coalesced over i)
    const size_t idx = (size_t)(i0 + r) * Ndim + j0 + c;
    float v = parts[idx];
#pragma unroll
    for (int s = 1; s < PARTS; ++s) v += parts[(size_t)s * tot + idx];
    t[r][c] = f1 * v * invS[j0 + c];
  }
  __syncthreads();
  for (int e = tid; e < 64 * 64; e += 256) {
    const int c = e >> 6, r = e & 63;  // c=i, r=l (coalesced over l)
    const size_t o = (size_t)(j0 + c) * Mdim + i0 + r;
    const float b = Tul[o] * invS[j0 + c];
    out[o] = fmaxf(t[r][c] + b, 0.f);
  }
}

// Z0[l][i] = bf16(Tul[i][l]*invS[i]); WB also writes f32 PulT (fallback only).
template <bool WB>
__global__ void make_z0(const float* __restrict__ Tul,
                        const float* __restrict__ invS,
                        float* __restrict__ PulT, short* __restrict__ Z0,
                        int n, int m) {
  __shared__ float t[64][65];
  const int ntj = m / 64;
  const int ti = blockIdx.x / ntj;
  const int tj = blockIdx.x % ntj;
  const int i0 = ti * 64, j0 = tj * 64;
  const int tid = threadIdx.x;
  for (int e = tid; e < 64 * 64; e += 256) {
    const int r = e >> 6, c = e & 63;
    t[r][c] = Tul[(size_t)(i0 + r) * m + j0 + c];
  }
  __syncthreads();
  for (int e = tid; e < 64 * 64; e += 256) {
    const int jr = e >> 6, ir = e & 63;
    const float p = t[ir][jr] * invS[i0 + ir];
    if (WB) PulT[(size_t)(j0 + jr) * n + i0 + ir] = p;
    Z0[(size_t)(j0 + jr) * n + i0 + ir] = f2bf(p);
  }
}

extern "C" void kernel_launch(void* const* d_in, const int* in_sizes, int n_in,
                              void* d_out, int out_size, void* d_ws, size_t ws_size,
                              hipStream_t stream) {
  const float* x = (const float*)d_in[0];
  const float* kn = (const float*)d_in[1];
  float* out = (float*)d_out;
  const int N = 4096, D = 1024, M = 512;
  const int NS = 1024;  // Rayleigh subset rows

  char* ws = (char*)d_ws;
  short* xb = (short*)ws;    ws += (size_t)N * D * 2;   // 8.4 MB
  short* kb = (short*)ws;    ws += (size_t)M * D * 2;   // 1.0 MB
  char* xq = ws;             ws += (size_t)N * D;       // 4.2 MB fp8 x (linear)
  short* T = (short*)ws;     ws += (size_t)N * N * 2;   // 33.5 MB (Tuu bf16)
  short* Z0 = (short*)ws;    ws += (size_t)M * N * 2;   // 4.2 MB
  short* Z1 = (short*)ws;    ws += (size_t)M * N * 2;   // 4.2 MB (fallback only)
  float* nb = (float*)ws;    ws += (size_t)N * 4;
  float* na = (float*)ws;    ws += (size_t)M * 4;
  float* invS = (float*)ws;  ws += (size_t)N * 4;
  float* rs = (float*)ws;    ws += (size_t)N * 4;
  float* lamf = (float*)ws;  ws += 64;
  float* pd = (float*)ws;    ws += 2 * 4096 * 4;
  float* prow = (float*)ws;  ws += (size_t)32 * N * 4;  // 512 KB col-partials
  float* parts = (float*)ws; ws += (size_t)M * N * 4 * 2;  // 16.8 MB splitK=2
  const size_t NEED = (size_t)(ws - (char*)d_ws);
  const bool EXT = ws_size >= NEED;
  float* bT = parts;  // fallback-only PulT aliases the (then-unused) parts
  float* Tul = out;   // d_out doubles as Tul scratch (overwritten at the end)

  prep_rows_all<<<N + M, 256, 0, stream>>>(x, kn, D, N, xb, kb, xq, nb, na);

  // Tul[i][l] = exp(-dp*sqrt(max(nb_i - 2 x.k + na_l, 0)))   [4096 x 512] f32
  gemm_nt<4, 1, false, 1, 128, 64, 64><<<(N / 128) * (M / 64), 256, 0, stream>>>(
      xb, kb, N, M, D, nb, na, nullptr, nullptr, nullptr, Tul);
  // T[i][j] = exp(-dp*sqrt(max(2nb_i - 2 x.x, 0))), diag 0  (128^2 2-phase,
  // MX-scaled fp8 32x32x64, 8 waves, 4 waves/SIMD; emits prow partials).
  gemm_nt8_tuu<<<(N / 128) * (N / 128), 512, 0, stream>>>(
      xq, N, D, nb, T, prow);

  rowsum_inv<<<N, 256, 0, stream>>>(Tul, prow, invS, rs, N, M);

  if (EXT) {
    make_z0<false><<<(N / 64) * (M / 64), 256, 0, stream>>>(
        Tul, invS, nullptr, Z0, N, M);
    // Single P-application + one-mode Richardson extrapolation:
    //   z1 = b P^T + b;  out = (1+f)*z1raw*invS + b,  f = lam/(1-lam),
    // lam = Rayleigh quotient with s = Puu*1 restricted to NS rows.
    pmatvec_dot<<<NS, 256, 0, stream>>>(T, rs, invS, pd, N, NS);
    dot_stage2<<<1, 256, 0, stream>>>(pd, NS, lamf);
    const dim3 sg((M / 128) * (N / 64), 2);  // (256, 2)
    gemm_nt<8, 8, false, 2, 128, 64, 64><<<sg, 512, 0, stream>>>(
        Z0, T, M, N, N, nullptr, nullptr, nullptr, nullptr, nullptr, parts);
    reduce_final1<2><<<(M / 64) * (N / 64), 256, 0, stream>>>(
        parts, Tul, invS, lamf, out, M, N);
  } else {
    make_z0<true><<<(N / 64) * (M / 64), 256, 0, stream>>>(
        Tul, invS, bT, Z0, N, M);
    // fallback: plain Jacobi, 34 iterations
    short* cur = Z0;
    short* nxt = Z1;
    const int NITER = 34;
    for (int it = 0; it < NITER; ++it) {
      if (it == NITER - 1) {
        gemm_nt<8, 2, true, 1, 128, 64, 64>
            <<<(M / 128) * (N / 64), 512, 0, stream>>>(
                cur, T, M, N, N, nullptr, nullptr, invS, bT, nullptr, out);
      } else {
        gemm_nt<8, 2, false, 1, 128, 64, 64>
            <<<(M / 128) * (N / 64), 512, 0, stream>>>(
                cur, T, M, N, N, nullptr, nullptr, invS, bT, nxt, nullptr);
      }
      short* t2 = cur; cur = nxt; nxt = t2;
    }
  }
}